// Round 14
// baseline (69.145 us; speedup 1.0000x reference)
//
#include <hip/hip_runtime.h>
#include <hip/hip_cooperative_groups.h>
#include <math.h>

namespace cg = cooperative_groups;

// SmoothLoss: per-batch masked exact 3-NN (drop self) cosine-sim loss.
// B=16, N=4096, K=3, mask = cls_label==1. Output: 1 f32 scalar.
//
// ONE cooperative dispatch (gpb=32 blocks/batch x 512 thr), zero memset:
// per-block scaled partials -> d_ws (plain stores), grid.sync(), block 0
// reduces and WRITES out[0] (deterministic order). Per block: register-
// retained binning (rank-returning count atomics -> non-atomic scatter)
// into LDS; wave-strided group assignment (wave w of block qb takes
// compacted group g = qb + gpb*w) spreads expansion-heavy corner groups
// across all CUs. Keys = float_bits(d2)&~0xFFF | orig_idx (order-
// preserving for d2>=0); exact scanned-box stop bound with truncation
// margin; 8-lane-parallel shell expansion. Tie-break = (d2, orig idx).

constexpr int      NC      = 7;
constexpr int      NCELL   = NC * NC * NC;   // 343
constexpr int      NPAD    = 384;            // scan padding (64 lanes x 6)
constexpr float    BOX     = 10.0f;
constexpr float    CELLH   = BOX / NC;
constexpr int      KNB     = 3;
constexpr int      TPB     = 512;
constexpr int      SUB     = 8;              // sub-lanes per query
constexpr int      SMAX    = 2048;           // LDS candidate capacity
constexpr int      UNR     = 8;              // points per thread (binning)
constexpr unsigned KEY_INF = 0xFFFFFFFFu;
constexpr unsigned IDX_MASK = 0xFFFu;        // 12 bits: npts <= 4096
constexpr unsigned DMASK    = ~IDX_MASK;

__device__ __forceinline__ unsigned umn(unsigned a, unsigned b) { return a < b ? a : b; }
__device__ __forceinline__ unsigned umx(unsigned a, unsigned b) { return a > b ? a : b; }

// branchless insert of key into sorted K0<=K1<=K2<=K3 (keep 4 smallest)
#define PINS(key, K0, K1, K2, K3)                          \
  do {                                                     \
    unsigned _c0 = umx(K0, (key)); K0 = umn(K0, (key));    \
    unsigned _c1 = umx(K1, _c0);   K1 = umn(K1, _c0);      \
    unsigned _c2 = umx(K2, _c1);   K2 = umn(K2, _c1);      \
    K3 = umn(K3, _c2);                                     \
  } while (0)

__device__ __forceinline__ int cell_of(float v) {
  int c = (int)(v * ((float)NC / BOX));
  return min(NC - 1, max(0, c));
}

__device__ __forceinline__ unsigned make_key(float dd, unsigned jbits) {
  return (__float_as_uint(dd) & DMASK) | jbits;
}

// shared epilogue: query jq, neighbor key (this sub-lane's) -> term
__device__ __forceinline__ float nbr_term(
    const float* __restrict__ pred, const float* __restrict__ target,
    int b, int npts, int jq, unsigned key)
{
  if (key == KEY_INF) return 0.0f;
  int j  = (int)(key & IDX_MASK);
  int gq = b * npts + jq;
  float px = pred[3 * gq + 0], py = pred[3 * gq + 1], pz = pred[3 * gq + 2];
  float pin = sqrtf(px * px + py * py + pz * pz + 1e-8f) + 1e-10f;
  float pinv = 1.0f / pin;
  px *= pinv; py *= pinv; pz *= pinv;
  int gj = b * npts + j;
  float nx = pred[3 * gj + 0], ny = pred[3 * gj + 1], nz = pred[3 * gj + 2];
  float nin = sqrtf(nx * nx + ny * ny + nz * nz + 1e-8f) + 1e-10f;
  float ninv = 1.0f / nin;
  float sim = fminf(fabsf((nx * px + ny * py + nz * pz) * ninv), 1.0f);
  float tx = target[3 * gq + 0], ty = target[3 * gq + 1], tz = target[3 * gq + 2];
  float ux = target[3 * gj + 0], uy = target[3 * gj + 1], uz = target[3 * gj + 2];
  float tsim = fminf(fabsf(ux * tx + uy * ty + uz * tz), 1.0f);
  float df = sim - tsim;
  return df * df;
}

// ---- per-group (8 queries x 8 sub-lanes): scan + merge + expansion ----
template <typename PC>
__device__ __forceinline__ float process_group(
    PC pc, const int* scs, int M, int m, int s,
    const float* __restrict__ pred, const float* __restrict__ target,
    int b, int npts)
{
  const bool active = (m < M);
  unsigned k0 = KEY_INF, k1 = KEY_INF, k2 = KEY_INF, k3 = KEY_INF;
  int jq = 0;

  if (active) {
    float4 qc = pc[m];
    const float qx = qc.x, qy = qc.y, qz = qc.z;
    jq = (int)(__float_as_uint(qc.w) & IDX_MASK);
    const int cx = cell_of(qx), cy = cell_of(qy), cz = cell_of(qz);
    const int xa1 = max(0, cx - 1), xb1 = min(NC - 1, cx + 1);

    // prefetch all 9 ring-0/1 row-span bounds
    int rk0[9], rk1[9];
    #pragma unroll
    for (int r = 0; r < 9; ++r) {
      int y2 = cy + (r % 3) - 1;
      int z2 = cz + (r / 3) - 1;
      if ((unsigned)y2 < (unsigned)NC && (unsigned)z2 < (unsigned)NC) {
        int base = (z2 * NC + y2) * NC;
        rk0[r] = scs[base + xa1];
        rk1[r] = scs[base + xb1 + 1];
      } else {
        rk0[r] = 0; rk1[r] = 0;
      }
    }

    // branchless scan: sub-lanes stride-8 within each row-span
    #pragma unroll
    for (int r = 0; r < 9; ++r) {
      for (int k = rk0[r] + s; k < rk1[r]; k += SUB) {
        float4 c = pc[k];
        float dx = c.x - qx, dy = c.y - qy, dz = c.z - qz;
        float dd = dx * dx + dy * dy + dz * dz;
        unsigned key = make_key(dd, __float_as_uint(c.w));
        PINS(key, k0, k1, k2, k3);
      }
    }

    // merge 8 disjoint sub-lane lists (within the 8-lane query subgroup)
    #pragma unroll
    for (int off = 1; off < SUB; off <<= 1) {
      unsigned e0 = (unsigned)__shfl_xor((int)k0, off);
      unsigned e1 = (unsigned)__shfl_xor((int)k1, off);
      unsigned e2 = (unsigned)__shfl_xor((int)k2, off);
      unsigned e3 = (unsigned)__shfl_xor((int)k3, off);
      PINS(e0, k0, k1, k2, k3);
      PINS(e1, k0, k1, k2, k3);
      PINS(e2, k0, k1, k2, k3);
      PINS(e3, k0, k1, k2, k3);
    }

    // exact shell expansion, 8-lane-parallel (true stragglers only)
    int rho = 1;
    while (rho < NC) {
      float dmin = 1e30f;
      int lo = cx - rho, hi = cx + rho;
      if (lo > 0)      dmin = fminf(dmin, qx - (float)lo * CELLH);
      if (hi < NC - 1) dmin = fminf(dmin, (float)(hi + 1) * CELLH - qx);
      lo = cy - rho; hi = cy + rho;
      if (lo > 0)      dmin = fminf(dmin, qy - (float)lo * CELLH);
      if (hi < NC - 1) dmin = fminf(dmin, (float)(hi + 1) * CELLH - qy);
      lo = cz - rho; hi = cz + rho;
      if (lo > 0)      dmin = fminf(dmin, qz - (float)lo * CELLH);
      if (hi < NC - 1) dmin = fminf(dmin, (float)(hi + 1) * CELLH - qz);
      bool stop;
      if (dmin >= 1e29f) stop = true;     // box covers whole domain
      else {
        float d3f = __uint_as_float(k3 & DMASK);  // NaN if KEY_INF -> no stop
        stop = (d3f <= dmin * dmin * 0.999f - 1e-3f);
      }
      if (stop) break;
      ++rho;

      unsigned g0 = KEY_INF, g1 = KEY_INF, g2 = KEY_INF, g3 = KEY_INF;
      auto scan_fresh = [&](int xa, int xb, int base) {
        int a0 = scs[base + xa];
        int a1 = scs[base + xb + 1];
        for (int k = a0 + s; k < a1; k += SUB) {
          float4 c = pc[k];
          float dx = c.x - qx, dy = c.y - qy, dz = c.z - qz;
          float dd = dx * dx + dy * dy + dz * dz;
          unsigned key = make_key(dd, __float_as_uint(c.w));
          PINS(key, g0, g1, g2, g3);
        }
      };

      for (int dz2 = -rho; dz2 <= rho; ++dz2) {
        int z2 = cz + dz2; if ((unsigned)z2 >= (unsigned)NC) continue;
        bool face_z = (dz2 == -rho || dz2 == rho);
        for (int dy2 = -rho; dy2 <= rho; ++dy2) {
          int y2 = cy + dy2; if ((unsigned)y2 >= (unsigned)NC) continue;
          int base = (z2 * NC + y2) * NC;
          if (face_z || dy2 == -rho || dy2 == rho) {
            scan_fresh(max(0, cx - rho), min(NC - 1, cx + rho), base);
          } else {
            if (cx - rho >= 0) scan_fresh(cx - rho, cx - rho, base);
            if (cx + rho < NC) scan_fresh(cx + rho, cx + rho, base);
          }
        }
      }

      // merge the 8 disjoint fresh lists, then fold (identical on all lanes)
      #pragma unroll
      for (int off = 1; off < SUB; off <<= 1) {
        unsigned e0 = (unsigned)__shfl_xor((int)g0, off);
        unsigned e1 = (unsigned)__shfl_xor((int)g1, off);
        unsigned e2 = (unsigned)__shfl_xor((int)g2, off);
        unsigned e3 = (unsigned)__shfl_xor((int)g3, off);
        PINS(e0, g0, g1, g2, g3);
        PINS(e1, g0, g1, g2, g3);
        PINS(e2, g0, g1, g2, g3);
        PINS(e3, g0, g1, g2, g3);
      }
      PINS(g0, k0, k1, k2, k3);
      PINS(g1, k0, k1, k2, k3);
      PINS(g2, k0, k1, k2, k3);
      PINS(g3, k0, k1, k2, k3);
    }
  }

  // k0 = self (d2==0, smallest key); sub-lanes 1..3 compute the 3 terms
  if (active && s >= 1 && s <= KNB) {
    unsigned key = (s == 1) ? k1 : (s == 2) ? k2 : k3;
    return nbr_term(pred, target, b, npts, jq, key);
  }
  return 0.0f;
}

// brute-force fallback: query by ORIGINAL index, global reads
__device__ __forceinline__ float process_brute_q(
    const float* __restrict__ coord, const int* __restrict__ cls,
    const float* __restrict__ pred, const float* __restrict__ target,
    int b, int npts, int jq, int s)
{
  const bool active = (jq < npts) && (cls[b * npts + jq] == 1);
  unsigned k0 = KEY_INF, k1 = KEY_INF, k2 = KEY_INF, k3 = KEY_INF;

  if (active) {
    const float* q = coord + 3 * ((size_t)b * npts + jq);
    float qx = q[0], qy = q[1], qz = q[2];
    for (int j = s; j < npts; j += SUB) {
      if (cls[b * npts + j] != 1) continue;
      const float* p = coord + 3 * ((size_t)b * npts + j);
      float dx = p[0] - qx, dy = p[1] - qy, dz = p[2] - qz;
      float dd = dx * dx + dy * dy + dz * dz;
      unsigned key = make_key(dd, (unsigned)j & IDX_MASK);
      PINS(key, k0, k1, k2, k3);
    }
    #pragma unroll
    for (int off = 1; off < SUB; off <<= 1) {
      unsigned e0 = (unsigned)__shfl_xor((int)k0, off);
      unsigned e1 = (unsigned)__shfl_xor((int)k1, off);
      unsigned e2 = (unsigned)__shfl_xor((int)k2, off);
      unsigned e3 = (unsigned)__shfl_xor((int)k3, off);
      PINS(e0, k0, k1, k2, k3);
      PINS(e1, k0, k1, k2, k3);
      PINS(e2, k0, k1, k2, k3);
      PINS(e3, k0, k1, k2, k3);
    }
  }

  if (active && s >= 1 && s <= KNB) {
    unsigned key = (s == 1) ? k1 : (s == 2) ? k2 : k3;
    return nbr_term(pred, target, b, npts, jq, key);
  }
  return 0.0f;
}

__global__ void __launch_bounds__(TPB) knn_fused_kernel(
    const float* __restrict__ pred,
    const float* __restrict__ coord,
    const float* __restrict__ target,
    const int* __restrict__ cls,
    float* __restrict__ out,
    float* __restrict__ partial,
    int npts, int nbatch, int gpb)
{
  __shared__ float4 scand[SMAX];
  __shared__ int    cnt_s[NPAD];
  __shared__ int    cstart[NPAD];
  __shared__ float  wsum[TPB / 64];

  const int tid = threadIdx.x;
  const int b   = blockIdx.x % nbatch;
  const int qb  = blockIdx.x / nbatch;     // [0, gpb)

  for (int c = tid; c < NPAD; c += TPB) cnt_s[c] = 0;
  __syncthreads();

  // ---- binning: one pass, rank from the count atomic's return value ----
  const int  base_j = tid * UNR;
  float fl[3 * UNR];
  int   lc[UNR];
  int   cellr[UNR];
  int   rank[UNR];
  unsigned msk = 0;
  const bool single = (npts <= TPB * UNR);

  if (single) {
    const bool fast = ((npts & 7) == 0) && (base_j + UNR <= npts);
    if (fast) {
      const float4* cf = (const float4*)(coord + 3 * ((size_t)b * npts + base_j));
      float4 v0 = cf[0], v1 = cf[1], v2 = cf[2], v3 = cf[3], v4 = cf[4], v5 = cf[5];
      fl[0]=v0.x; fl[1]=v0.y; fl[2]=v0.z; fl[3]=v0.w;
      fl[4]=v1.x; fl[5]=v1.y; fl[6]=v1.z; fl[7]=v1.w;
      fl[8]=v2.x; fl[9]=v2.y; fl[10]=v2.z; fl[11]=v2.w;
      fl[12]=v3.x; fl[13]=v3.y; fl[14]=v3.z; fl[15]=v3.w;
      fl[16]=v4.x; fl[17]=v4.y; fl[18]=v4.z; fl[19]=v4.w;
      fl[20]=v5.x; fl[21]=v5.y; fl[22]=v5.z; fl[23]=v5.w;
      const int4* ci = (const int4*)(cls + (size_t)b * npts + base_j);
      int4 a0 = ci[0], a1 = ci[1];
      lc[0]=a0.x; lc[1]=a0.y; lc[2]=a0.z; lc[3]=a0.w;
      lc[4]=a1.x; lc[5]=a1.y; lc[6]=a1.z; lc[7]=a1.w;
    } else {
      #pragma unroll
      for (int u = 0; u < UNR; ++u) {
        int j = base_j + u;
        if (j < npts) {
          lc[u] = cls[(size_t)b * npts + j];
          fl[3*u+0] = coord[3 * ((size_t)b * npts + j) + 0];
          fl[3*u+1] = coord[3 * ((size_t)b * npts + j) + 1];
          fl[3*u+2] = coord[3 * ((size_t)b * npts + j) + 2];
        } else lc[u] = 0;
      }
    }
    #pragma unroll
    for (int u = 0; u < UNR; ++u) {
      if (lc[u] == 1) {
        msk |= (1u << u);
        cellr[u] = (cell_of(fl[3*u+2]) * NC + cell_of(fl[3*u+1])) * NC + cell_of(fl[3*u+0]);
        rank[u] = atomicAdd(&cnt_s[cellr[u]], 1);
      }
    }
  } else {
    // off-spec shape: count only (for M); scan path falls back to brute
    for (int j = tid; j < npts; j += TPB) {
      if (cls[(size_t)b * npts + j] == 1) {
        const float* p = coord + 3 * ((size_t)b * npts + j);
        int cell = (cell_of(p[2]) * NC + cell_of(p[1])) * NC + cell_of(p[0]);
        atomicAdd(&cnt_s[cell], 1);
      }
    }
  }
  __syncthreads();

  // single-wave exclusive scan over NPAD padded counts (6 cells per lane)
  if (tid < 64) {
    const int base = tid * (NPAD / 64);
    int v[NPAD / 64];
    int tot = 0;
    #pragma unroll
    for (int u = 0; u < NPAD / 64; ++u) { v[u] = cnt_s[base + u]; tot += v[u]; }
    int x = tot;
    #pragma unroll
    for (int off = 1; off < 64; off <<= 1) {
      int y = __shfl_up(x, off);
      if (tid >= off) x += y;
    }
    int run = x - tot;  // exclusive
    #pragma unroll
    for (int u = 0; u < NPAD / 64; ++u) { cstart[base + u] = run; run += v[u]; }
  }
  __syncthreads();

  const int  M      = cstart[NCELL];   // pads count zero -> cstart[NCELL] == M
  const bool lds_ok = single && (M <= SMAX);

  if (lds_ok) {
    // non-atomic scatter: slot = cstart[cell] + rank (rank from count pass)
    #pragma unroll
    for (int u = 0; u < UNR; ++u) {
      if (msk & (1u << u)) {
        scand[cstart[cellr[u]] + rank[u]] =
          make_float4(fl[3*u+0], fl[3*u+1], fl[3*u+2],
                      __uint_as_float((unsigned)(base_j + u)));
      }
    }
  }
  __syncthreads();

  // ---- wave-strided groups: wave w takes g = qb + gpb*w (+8*gpb steps) ----
  const int w    = tid >> 6;             // wave id [0,8)
  const int lane = tid & 63;
  const int s    = lane & 7;             // sub-lane within query
  const int qi   = lane >> 3;            // query within group [0,8)
  const int slot = qb + gpb * w;
  const int gstride = 8 * gpb;

  float contrib = 0.0f;
  if (lds_ok) {
    const int ngroups = (M + 7) >> 3;
    for (int g = slot; g < ngroups; g += gstride)
      contrib += process_group(scand, cstart, M, g * 8 + qi, s,
                               pred, target, b, npts);
  } else {
    const int ngroups = (npts + 7) >> 3;
    for (int g = slot; g < ngroups; g += gstride)
      contrib += process_brute_q(coord, cls, pred, target, b, npts,
                                 g * 8 + qi, s);
  }

  #pragma unroll
  for (int off = 32; off > 0; off >>= 1) contrib += __shfl_down(contrib, off);
  if (lane == 0) wsum[w] = contrib;
  __syncthreads();
  if (tid == 0) {
    float se = 0.f;
    #pragma unroll
    for (int wv = 0; wv < TPB / 64; ++wv) se += wsum[wv];
    partial[blockIdx.x] =
      (M > 0) ? se / ((float)M * (float)KNB * (float)nbatch) : 0.0f;
  }

  // ---- grid-wide sync, then block 0 reduces partials and writes out ----
  cg::this_grid().sync();

  if (blockIdx.x == 0) {
    float s2 = 0.0f;
    for (int i = tid; i < (int)gridDim.x; i += TPB) s2 += partial[i];
    #pragma unroll
    for (int off = 32; off > 0; off >>= 1) s2 += __shfl_down(s2, off);
    if (lane == 0) wsum[w] = s2;
    __syncthreads();
    if (tid == 0) {
      float tot = 0.f;
      #pragma unroll
      for (int wv = 0; wv < TPB / 64; ++wv) tot += wsum[wv];
      out[0] = tot;
    }
  }
}

extern "C" void kernel_launch(void* const* d_in, const int* in_sizes, int n_in,
                              void* d_out, int out_size, void* d_ws, size_t ws_size,
                              hipStream_t stream) {
  const float* pred   = (const float*)d_in[0];
  const float* coord  = (const float*)d_in[1];
  const float* target = (const float*)d_in[2];
  // d_in[3] = nums (unused; all N)
  const int*   cls    = (const int*)d_in[4];
  float* out = (float*)d_out;

  const int n    = in_sizes[0] / 3;
  const int nb   = in_sizes[3];
  const int npts = n / nb;

  int gpb = 512 / nb;                    // blocks per batch
  if (gpb < 1) gpb = 1;
  int grid = gpb * nb;

  float* partial = (float*)d_ws;         // grid floats

  void* args[] = { (void*)&pred, (void*)&coord, (void*)&target, (void*)&cls,
                   (void*)&out, (void*)&partial,
                   (void*)&npts, (void*)&nb, (void*)&gpb };
  hipLaunchCooperativeKernel((const void*)knn_fused_kernel,
                             dim3(grid), dim3(TPB), args, 0, stream);
}

// Round 15
// 23.217 us; speedup vs baseline: 2.9782x; 2.9782x over previous
//
#include <hip/hip_runtime.h>
#include <math.h>

// SmoothLoss: per-batch masked exact 3-NN (drop self) cosine-sim loss.
// B=16, N=4096, K=3, mask = cls_label==1. Output: 1 f32 scalar.
//
// Two graph nodes: hipMemsetAsync(out) + fused kernel (gpb=32 blocks/batch
// x 512 thr). [Round 14 showed cooperative grid.sync costs ~40us -- dead.]
// Per block: register-retained binning into LDS with DUAL-PARITY count
// histograms (cnt_s[tid&1][cell] halves same-cell atomic collisions; scan
// sums both; parity-1 scatter offsets by cnt_s[0][cell]); rank-returning
// atomics -> non-atomic scatter. Wave-strided group assignment (wave w of
// block qb takes compacted group g = qb + gpb*w) spreads expansion-heavy
// corner groups across all CUs. Keys = float_bits(d2)&~0xFFF | orig_idx
// (order-preserving for d2>=0); exact scanned-box stop bound with
// truncation margin; 8-lane-parallel shell expansion. Tie-break =
// (d2, original index). Block partial -> atomicAdd(out).

constexpr int      NC      = 7;
constexpr int      NCELL   = NC * NC * NC;   // 343
constexpr int      NPAD    = 384;            // scan padding (64 lanes x 6)
constexpr float    BOX     = 10.0f;
constexpr float    CELLH   = BOX / NC;
constexpr int      KNB     = 3;
constexpr int      TPB     = 512;
constexpr int      SUB     = 8;              // sub-lanes per query
constexpr int      SMAX    = 2048;           // LDS candidate capacity
constexpr int      UNR     = 8;              // points per thread (binning)
constexpr unsigned KEY_INF = 0xFFFFFFFFu;
constexpr unsigned IDX_MASK = 0xFFFu;        // 12 bits: npts <= 4096
constexpr unsigned DMASK    = ~IDX_MASK;

__device__ __forceinline__ unsigned umn(unsigned a, unsigned b) { return a < b ? a : b; }
__device__ __forceinline__ unsigned umx(unsigned a, unsigned b) { return a > b ? a : b; }

// branchless insert of key into sorted K0<=K1<=K2<=K3 (keep 4 smallest)
#define PINS(key, K0, K1, K2, K3)                          \
  do {                                                     \
    unsigned _c0 = umx(K0, (key)); K0 = umn(K0, (key));    \
    unsigned _c1 = umx(K1, _c0);   K1 = umn(K1, _c0);      \
    unsigned _c2 = umx(K2, _c1);   K2 = umn(K2, _c1);      \
    K3 = umn(K3, _c2);                                     \
  } while (0)

__device__ __forceinline__ int cell_of(float v) {
  int c = (int)(v * ((float)NC / BOX));
  return min(NC - 1, max(0, c));
}

__device__ __forceinline__ unsigned make_key(float dd, unsigned jbits) {
  return (__float_as_uint(dd) & DMASK) | jbits;
}

// shared epilogue: query jq, neighbor key (this sub-lane's) -> term
__device__ __forceinline__ float nbr_term(
    const float* __restrict__ pred, const float* __restrict__ target,
    int b, int npts, int jq, unsigned key)
{
  if (key == KEY_INF) return 0.0f;
  int j  = (int)(key & IDX_MASK);
  int gq = b * npts + jq;
  float px = pred[3 * gq + 0], py = pred[3 * gq + 1], pz = pred[3 * gq + 2];
  float pin = sqrtf(px * px + py * py + pz * pz + 1e-8f) + 1e-10f;
  float pinv = 1.0f / pin;
  px *= pinv; py *= pinv; pz *= pinv;
  int gj = b * npts + j;
  float nx = pred[3 * gj + 0], ny = pred[3 * gj + 1], nz = pred[3 * gj + 2];
  float nin = sqrtf(nx * nx + ny * ny + nz * nz + 1e-8f) + 1e-10f;
  float ninv = 1.0f / nin;
  float sim = fminf(fabsf((nx * px + ny * py + nz * pz) * ninv), 1.0f);
  float tx = target[3 * gq + 0], ty = target[3 * gq + 1], tz = target[3 * gq + 2];
  float ux = target[3 * gj + 0], uy = target[3 * gj + 1], uz = target[3 * gj + 2];
  float tsim = fminf(fabsf(ux * tx + uy * ty + uz * tz), 1.0f);
  float df = sim - tsim;
  return df * df;
}

// ---- per-group (8 queries x 8 sub-lanes): scan + merge + expansion ----
template <typename PC>
__device__ __forceinline__ float process_group(
    PC pc, const int* scs, int M, int m, int s,
    const float* __restrict__ pred, const float* __restrict__ target,
    int b, int npts)
{
  const bool active = (m < M);
  unsigned k0 = KEY_INF, k1 = KEY_INF, k2 = KEY_INF, k3 = KEY_INF;
  int jq = 0;

  if (active) {
    float4 qc = pc[m];
    const float qx = qc.x, qy = qc.y, qz = qc.z;
    jq = (int)(__float_as_uint(qc.w) & IDX_MASK);
    const int cx = cell_of(qx), cy = cell_of(qy), cz = cell_of(qz);
    const int xa1 = max(0, cx - 1), xb1 = min(NC - 1, cx + 1);

    // prefetch all 9 ring-0/1 row-span bounds
    int rk0[9], rk1[9];
    #pragma unroll
    for (int r = 0; r < 9; ++r) {
      int y2 = cy + (r % 3) - 1;
      int z2 = cz + (r / 3) - 1;
      if ((unsigned)y2 < (unsigned)NC && (unsigned)z2 < (unsigned)NC) {
        int base = (z2 * NC + y2) * NC;
        rk0[r] = scs[base + xa1];
        rk1[r] = scs[base + xb1 + 1];
      } else {
        rk0[r] = 0; rk1[r] = 0;
      }
    }

    // branchless scan: sub-lanes stride-8 within each row-span
    #pragma unroll
    for (int r = 0; r < 9; ++r) {
      for (int k = rk0[r] + s; k < rk1[r]; k += SUB) {
        float4 c = pc[k];
        float dx = c.x - qx, dy = c.y - qy, dz = c.z - qz;
        float dd = dx * dx + dy * dy + dz * dz;
        unsigned key = make_key(dd, __float_as_uint(c.w));
        PINS(key, k0, k1, k2, k3);
      }
    }

    // merge 8 disjoint sub-lane lists (within the 8-lane query subgroup)
    #pragma unroll
    for (int off = 1; off < SUB; off <<= 1) {
      unsigned e0 = (unsigned)__shfl_xor((int)k0, off);
      unsigned e1 = (unsigned)__shfl_xor((int)k1, off);
      unsigned e2 = (unsigned)__shfl_xor((int)k2, off);
      unsigned e3 = (unsigned)__shfl_xor((int)k3, off);
      PINS(e0, k0, k1, k2, k3);
      PINS(e1, k0, k1, k2, k3);
      PINS(e2, k0, k1, k2, k3);
      PINS(e3, k0, k1, k2, k3);
    }

    // exact shell expansion, 8-lane-parallel (true stragglers only)
    int rho = 1;
    while (rho < NC) {
      float dmin = 1e30f;
      int lo = cx - rho, hi = cx + rho;
      if (lo > 0)      dmin = fminf(dmin, qx - (float)lo * CELLH);
      if (hi < NC - 1) dmin = fminf(dmin, (float)(hi + 1) * CELLH - qx);
      lo = cy - rho; hi = cy + rho;
      if (lo > 0)      dmin = fminf(dmin, qy - (float)lo * CELLH);
      if (hi < NC - 1) dmin = fminf(dmin, (float)(hi + 1) * CELLH - qy);
      lo = cz - rho; hi = cz + rho;
      if (lo > 0)      dmin = fminf(dmin, qz - (float)lo * CELLH);
      if (hi < NC - 1) dmin = fminf(dmin, (float)(hi + 1) * CELLH - qz);
      bool stop;
      if (dmin >= 1e29f) stop = true;     // box covers whole domain
      else {
        float d3f = __uint_as_float(k3 & DMASK);  // NaN if KEY_INF -> no stop
        stop = (d3f <= dmin * dmin * 0.999f - 1e-3f);
      }
      if (stop) break;
      ++rho;

      unsigned g0 = KEY_INF, g1 = KEY_INF, g2 = KEY_INF, g3 = KEY_INF;
      auto scan_fresh = [&](int xa, int xb, int base) {
        int a0 = scs[base + xa];
        int a1 = scs[base + xb + 1];
        for (int k = a0 + s; k < a1; k += SUB) {
          float4 c = pc[k];
          float dx = c.x - qx, dy = c.y - qy, dz = c.z - qz;
          float dd = dx * dx + dy * dy + dz * dz;
          unsigned key = make_key(dd, __float_as_uint(c.w));
          PINS(key, g0, g1, g2, g3);
        }
      };

      for (int dz2 = -rho; dz2 <= rho; ++dz2) {
        int z2 = cz + dz2; if ((unsigned)z2 >= (unsigned)NC) continue;
        bool face_z = (dz2 == -rho || dz2 == rho);
        for (int dy2 = -rho; dy2 <= rho; ++dy2) {
          int y2 = cy + dy2; if ((unsigned)y2 >= (unsigned)NC) continue;
          int base = (z2 * NC + y2) * NC;
          if (face_z || dy2 == -rho || dy2 == rho) {
            scan_fresh(max(0, cx - rho), min(NC - 1, cx + rho), base);
          } else {
            if (cx - rho >= 0) scan_fresh(cx - rho, cx - rho, base);
            if (cx + rho < NC) scan_fresh(cx + rho, cx + rho, base);
          }
        }
      }

      // merge the 8 disjoint fresh lists, then fold (identical on all lanes)
      #pragma unroll
      for (int off = 1; off < SUB; off <<= 1) {
        unsigned e0 = (unsigned)__shfl_xor((int)g0, off);
        unsigned e1 = (unsigned)__shfl_xor((int)g1, off);
        unsigned e2 = (unsigned)__shfl_xor((int)g2, off);
        unsigned e3 = (unsigned)__shfl_xor((int)g3, off);
        PINS(e0, g0, g1, g2, g3);
        PINS(e1, g0, g1, g2, g3);
        PINS(e2, g0, g1, g2, g3);
        PINS(e3, g0, g1, g2, g3);
      }
      PINS(g0, k0, k1, k2, k3);
      PINS(g1, k0, k1, k2, k3);
      PINS(g2, k0, k1, k2, k3);
      PINS(g3, k0, k1, k2, k3);
    }
  }

  // k0 = self (d2==0, smallest key); sub-lanes 1..3 compute the 3 terms
  if (active && s >= 1 && s <= KNB) {
    unsigned key = (s == 1) ? k1 : (s == 2) ? k2 : k3;
    return nbr_term(pred, target, b, npts, jq, key);
  }
  return 0.0f;
}

// brute-force fallback: query by ORIGINAL index, global reads
__device__ __forceinline__ float process_brute_q(
    const float* __restrict__ coord, const int* __restrict__ cls,
    const float* __restrict__ pred, const float* __restrict__ target,
    int b, int npts, int jq, int s)
{
  const bool active = (jq < npts) && (cls[b * npts + jq] == 1);
  unsigned k0 = KEY_INF, k1 = KEY_INF, k2 = KEY_INF, k3 = KEY_INF;

  if (active) {
    const float* q = coord + 3 * ((size_t)b * npts + jq);
    float qx = q[0], qy = q[1], qz = q[2];
    for (int j = s; j < npts; j += SUB) {
      if (cls[b * npts + j] != 1) continue;
      const float* p = coord + 3 * ((size_t)b * npts + j);
      float dx = p[0] - qx, dy = p[1] - qy, dz = p[2] - qz;
      float dd = dx * dx + dy * dy + dz * dz;
      unsigned key = make_key(dd, (unsigned)j & IDX_MASK);
      PINS(key, k0, k1, k2, k3);
    }
    #pragma unroll
    for (int off = 1; off < SUB; off <<= 1) {
      unsigned e0 = (unsigned)__shfl_xor((int)k0, off);
      unsigned e1 = (unsigned)__shfl_xor((int)k1, off);
      unsigned e2 = (unsigned)__shfl_xor((int)k2, off);
      unsigned e3 = (unsigned)__shfl_xor((int)k3, off);
      PINS(e0, k0, k1, k2, k3);
      PINS(e1, k0, k1, k2, k3);
      PINS(e2, k0, k1, k2, k3);
      PINS(e3, k0, k1, k2, k3);
    }
  }

  if (active && s >= 1 && s <= KNB) {
    unsigned key = (s == 1) ? k1 : (s == 2) ? k2 : k3;
    return nbr_term(pred, target, b, npts, jq, key);
  }
  return 0.0f;
}

__global__ void __launch_bounds__(TPB) knn_fused_kernel(
    const float* __restrict__ pred,
    const float* __restrict__ coord,
    const float* __restrict__ target,
    const int* __restrict__ cls,
    float* __restrict__ out,
    int npts, int nbatch, int gpb)
{
  __shared__ float4 scand[SMAX];
  __shared__ int    cnt_s[2][NPAD];     // dual-parity histograms
  __shared__ int    cstart[NPAD];
  __shared__ float  wsum[TPB / 64];

  const int tid = threadIdx.x;
  const int b   = blockIdx.x % nbatch;
  const int qb  = blockIdx.x / nbatch;     // [0, gpb)
  const int par = tid & 1;

  for (int c = tid; c < NPAD; c += TPB) { cnt_s[0][c] = 0; cnt_s[1][c] = 0; }
  __syncthreads();

  // ---- binning: one pass, rank from the count atomic's return value ----
  const int  base_j = tid * UNR;
  float fl[3 * UNR];
  int   lc[UNR];
  int   cellr[UNR];
  int   rank[UNR];
  unsigned msk = 0;
  const bool single = (npts <= TPB * UNR);

  if (single) {
    const bool fast = ((npts & 7) == 0) && (base_j + UNR <= npts);
    if (fast) {
      const float4* cf = (const float4*)(coord + 3 * ((size_t)b * npts + base_j));
      float4 v0 = cf[0], v1 = cf[1], v2 = cf[2], v3 = cf[3], v4 = cf[4], v5 = cf[5];
      fl[0]=v0.x; fl[1]=v0.y; fl[2]=v0.z; fl[3]=v0.w;
      fl[4]=v1.x; fl[5]=v1.y; fl[6]=v1.z; fl[7]=v1.w;
      fl[8]=v2.x; fl[9]=v2.y; fl[10]=v2.z; fl[11]=v2.w;
      fl[12]=v3.x; fl[13]=v3.y; fl[14]=v3.z; fl[15]=v3.w;
      fl[16]=v4.x; fl[17]=v4.y; fl[18]=v4.z; fl[19]=v4.w;
      fl[20]=v5.x; fl[21]=v5.y; fl[22]=v5.z; fl[23]=v5.w;
      const int4* ci = (const int4*)(cls + (size_t)b * npts + base_j);
      int4 a0 = ci[0], a1 = ci[1];
      lc[0]=a0.x; lc[1]=a0.y; lc[2]=a0.z; lc[3]=a0.w;
      lc[4]=a1.x; lc[5]=a1.y; lc[6]=a1.z; lc[7]=a1.w;
    } else {
      #pragma unroll
      for (int u = 0; u < UNR; ++u) {
        int j = base_j + u;
        if (j < npts) {
          lc[u] = cls[(size_t)b * npts + j];
          fl[3*u+0] = coord[3 * ((size_t)b * npts + j) + 0];
          fl[3*u+1] = coord[3 * ((size_t)b * npts + j) + 1];
          fl[3*u+2] = coord[3 * ((size_t)b * npts + j) + 2];
        } else lc[u] = 0;
      }
    }
    #pragma unroll
    for (int u = 0; u < UNR; ++u) {
      if (lc[u] == 1) {
        msk |= (1u << u);
        cellr[u] = (cell_of(fl[3*u+2]) * NC + cell_of(fl[3*u+1])) * NC + cell_of(fl[3*u+0]);
        rank[u] = atomicAdd(&cnt_s[par][cellr[u]], 1);
      }
    }
  } else {
    // off-spec shape: count only (for M); scan path falls back to brute
    for (int j = tid; j < npts; j += TPB) {
      if (cls[(size_t)b * npts + j] == 1) {
        const float* p = coord + 3 * ((size_t)b * npts + j);
        int cell = (cell_of(p[2]) * NC + cell_of(p[1])) * NC + cell_of(p[0]);
        atomicAdd(&cnt_s[0][cell], 1);
      }
    }
  }
  __syncthreads();

  // single-wave exclusive scan over NPAD padded totals (6 cells per lane)
  if (tid < 64) {
    const int base = tid * (NPAD / 64);
    int v[NPAD / 64];
    int tot = 0;
    #pragma unroll
    for (int u = 0; u < NPAD / 64; ++u) {
      v[u] = cnt_s[0][base + u] + cnt_s[1][base + u];
      tot += v[u];
    }
    int x = tot;
    #pragma unroll
    for (int off = 1; off < 64; off <<= 1) {
      int y = __shfl_up(x, off);
      if (tid >= off) x += y;
    }
    int run = x - tot;  // exclusive
    #pragma unroll
    for (int u = 0; u < NPAD / 64; ++u) { cstart[base + u] = run; run += v[u]; }
  }
  __syncthreads();

  const int  M      = cstart[NCELL];   // pads count zero -> cstart[NCELL] == M
  const bool lds_ok = single && (M <= SMAX);

  if (lds_ok) {
    // non-atomic scatter: slot = cstart[cell] + (par ? cnt0[cell] : 0) + rank
    #pragma unroll
    for (int u = 0; u < UNR; ++u) {
      if (msk & (1u << u)) {
        int slot = cstart[cellr[u]] + rank[u]
                 + (par ? cnt_s[0][cellr[u]] : 0);
        scand[slot] = make_float4(fl[3*u+0], fl[3*u+1], fl[3*u+2],
                                  __uint_as_float((unsigned)(base_j + u)));
      }
    }
  }
  __syncthreads();

  // ---- wave-strided groups: wave w takes g = qb + gpb*w (+8*gpb steps) ----
  const int w    = tid >> 6;             // wave id [0,8)
  const int lane = tid & 63;
  const int s    = lane & 7;             // sub-lane within query
  const int qi   = lane >> 3;            // query within group [0,8)
  const int slot = qb + gpb * w;
  const int gstride = 8 * gpb;

  float contrib = 0.0f;
  if (lds_ok) {
    const int ngroups = (M + 7) >> 3;
    for (int g = slot; g < ngroups; g += gstride)
      contrib += process_group(scand, cstart, M, g * 8 + qi, s,
                               pred, target, b, npts);
  } else {
    const int ngroups = (npts + 7) >> 3;
    for (int g = slot; g < ngroups; g += gstride)
      contrib += process_brute_q(coord, cls, pred, target, b, npts,
                                 g * 8 + qi, s);
  }

  #pragma unroll
  for (int off = 32; off > 0; off >>= 1) contrib += __shfl_down(contrib, off);
  if (lane == 0) wsum[w] = contrib;
  __syncthreads();
  if (tid == 0 && M > 0) {
    float se = 0.f;
    #pragma unroll
    for (int wv = 0; wv < TPB / 64; ++wv) se += wsum[wv];
    atomicAdd(out, se / ((float)M * (float)KNB * (float)nbatch));
  }
}

extern "C" void kernel_launch(void* const* d_in, const int* in_sizes, int n_in,
                              void* d_out, int out_size, void* d_ws, size_t ws_size,
                              hipStream_t stream) {
  const float* pred   = (const float*)d_in[0];
  const float* coord  = (const float*)d_in[1];
  const float* target = (const float*)d_in[2];
  // d_in[3] = nums (unused; all N)
  const int*   cls    = (const int*)d_in[4];
  float* out = (float*)d_out;

  const int n    = in_sizes[0] / 3;
  const int nb   = in_sizes[3];
  const int npts = n / nb;

  int gpb = 512 / nb;                    // blocks per batch
  if (gpb < 1) gpb = 1;
  const int grid = gpb * nb;

  hipMemsetAsync(out, 0, sizeof(float), stream);
  hipLaunchKernelGGL(knn_fused_kernel, dim3(grid), dim3(TPB), 0, stream,
                     pred, coord, target, cls, out, npts, nb, gpb);
}